// Round 4
// baseline (674.430 us; speedup 1.0000x reference)
//
#include <hip/hip_runtime.h>
#include <math.h>

#define DD 1024
#define RR 64
#define NTH 512   // 8 waves, 16 rows/block, wave w owns k in [w*128, w*128+128)

typedef _Float16 f16x8 __attribute__((ext_vector_type(8)));
typedef _Float16 h2    __attribute__((ext_vector_type(2)));
typedef float    f32x4 __attribute__((ext_vector_type(4)));

__device__ __forceinline__ f32x4 mfma16(f16x8 a, f16x8 b, f32x4 c) {
    return __builtin_amdgcn_mfma_f32_16x16x32_f16(a, b, c, 0, 0, 0);
}

// prep: hi-only fp16 fragments, matrices scaled x32. (unchanged from round 3)
// U  frags [kt0..31][Nt0..3][l][e]:  U[k][col], k=kt*32+(l>>4)*8+e, col=Nt*16+(l&15)
// Vw frags: same layout, at +65536
// Wt frags [Nt0..63][ktr0..1][l][e]: W[r][n],  n=Nt*16+(l&15), r=ktr*32+(l>>4)*8+e  (+131072)
__global__ void prep_kernel(const float* __restrict__ U, const float* __restrict__ Vw,
                            const float* __restrict__ Wm, _Float16* __restrict__ ws)
{
    int tid = blockIdx.x * blockDim.x + threadIdx.x;
    if (tid >= 3 * 65536) return;
    int m = tid >> 16;
    int r = tid & 65535;
    int l = (r >> 3) & 63;
    int e = r & 7;
    int tile = r >> 9;
    float val;
    if (m < 2) {
        int kt = tile >> 2, Nt = tile & 3;
        int k = kt * 32 + (l >> 4) * 8 + e;
        int col = Nt * 16 + (l & 15);
        val = (m == 0 ? U : Vw)[k * RR + col] * 32.0f;
    } else {
        int Nt = tile >> 1, ktr = tile & 1;
        int n = Nt * 16 + (l & 15);
        int rr = ktr * 32 + (l >> 4) * 8 + e;
        val = Wm[rr * DD + n] * 32.0f;
    }
    ws[m * 65536 + r] = (_Float16)val;
}

__global__ __launch_bounds__(NTH, 4)   // 4 waves/EU -> VGPR cap 128, 2 blocks/CU
void yoshida4(const float* __restrict__ x_in, const float* __restrict__ v_in,
              const float* __restrict__ force, const int* __restrict__ steps_p,
              const _Float16* __restrict__ ws, float* __restrict__ out, long vout_off,
              float c1, float c2, float d1, float d2)
{
    __shared__ float red_q[8 * 16 * 68];      // [wave][batch-row][r] stride 68
    __shared__ float red_p[8 * 16 * 68];
    __shared__ _Float16 qh_s[2 * 64 * 8];     // qhat^T B-frags (hi fp16)
    __shared__ float xn_s[8 * 16];
    __shared__ float sing_s[16];

    const int tid = threadIdx.x;
    const int w = tid >> 6, l = tid & 63;
    const int m16 = l & 15, g = l >> 4;
    const long row0 = (long)blockIdx.x * 16;

    const _Float16* __restrict__ Uf = ws;
    const _Float16* __restrict__ Vf = ws + 65536;
    const _Float16* __restrict__ Wf = ws + 131072;

    float xr[32], vr[32];     // wave's k-eighth of 16 rows, A-frag layout
    h2 fh[16];                // force slice, fp16 pairs

    {
        const float* xp = x_in + (row0 + m16) * DD + w * 128 + g * 8;
        const float* vp = v_in + (row0 + m16) * DD + w * 128 + g * 8;
        const float* fp = force + (row0 + m16) * DD + w * 128 + g * 8;
#pragma unroll
        for (int kt = 0; kt < 4; ++kt) {
            float4 a = *(const float4*)(xp + kt * 32);
            float4 b = *(const float4*)(xp + kt * 32 + 4);
            xr[kt*8+0]=a.x; xr[kt*8+1]=a.y; xr[kt*8+2]=a.z; xr[kt*8+3]=a.w;
            xr[kt*8+4]=b.x; xr[kt*8+5]=b.y; xr[kt*8+6]=b.z; xr[kt*8+7]=b.w;
            float4 c = *(const float4*)(vp + kt * 32);
            float4 d = *(const float4*)(vp + kt * 32 + 4);
            vr[kt*8+0]=c.x; vr[kt*8+1]=c.y; vr[kt*8+2]=c.z; vr[kt*8+3]=c.w;
            vr[kt*8+4]=d.x; vr[kt*8+5]=d.y; vr[kt*8+6]=d.z; vr[kt*8+7]=d.w;
            float4 e4 = *(const float4*)(fp + kt * 32);
            float4 e5 = *(const float4*)(fp + kt * 32 + 4);
            fh[kt*4+0] = (h2){(_Float16)e4.x, (_Float16)e4.y};
            fh[kt*4+1] = (h2){(_Float16)e4.z, (_Float16)e4.w};
            fh[kt*4+2] = (h2){(_Float16)e5.x, (_Float16)e5.y};
            fh[kt*4+3] = (h2){(_Float16)e5.z, (_Float16)e5.w};
        }
    }
    const int nsteps = steps_p[0];

    for (int s = 0; s < nsteps; ++s) {
#pragma unroll 1
        for (int sub = 0; sub < 3; ++sub) {
            const float cdt = (sub == 0) ? c1 : c2;
            const float ddt = (sub == 1) ? d2 : d1;

            // ---- drift x += cdt*v (registers) + ||x||^2 partials ----
            float part = 0.0f;
#pragma unroll
            for (int i = 0; i < 32; ++i) {
                float xn = fmaf(cdt, vr[i], xr[i]);
                xr[i] = xn;
                part = fmaf(xn, xn, part);
            }
            part += __shfl_xor(part, 16);
            part += __shfl_xor(part, 32);
            if (l < 16) xn_s[w * 16 + l] = part;

            // ---- Q = v @ U' over wave's k-eighth (A split hi/lo, B hi) ----
            {
                f32x4 q0 = {0,0,0,0}, q1 = {0,0,0,0}, q2 = {0,0,0,0}, q3 = {0,0,0,0};
#pragma unroll
                for (int kt = 0; kt < 4; ++kt) {
                    const f16x8* UB = (const f16x8*)Uf + ((w * 4 + kt) * 4) * 64 + l;
                    f16x8 b0 = UB[0], b1 = UB[64], b2 = UB[128], b3 = UB[192];
                    f16x8 ah, al;
#pragma unroll
                    for (int e = 0; e < 8; ++e) {
                        float t = vr[kt * 8 + e];
                        _Float16 h = (_Float16)t;
                        ah[e] = h;
                        al[e] = (_Float16)(t - (float)h);
                    }
                    q0 = mfma16(ah, b0, q0); q1 = mfma16(ah, b1, q1);
                    q2 = mfma16(ah, b2, q2); q3 = mfma16(ah, b3, q3);
                    q0 = mfma16(al, b0, q0); q1 = mfma16(al, b1, q1);
                    q2 = mfma16(al, b2, q2); q3 = mfma16(al, b3, q3);
                }
#pragma unroll
                for (int j = 0; j < 4; ++j) {
                    int base = w * 1088 + (g * 4 + j) * 68 + m16;
                    red_q[base]      = q0[j];
                    red_q[base + 16] = q1[j];
                    red_q[base + 32] = q2[j];
                    red_q[base + 48] = q3[j];
                }
            }
            // ---- P = x @ Vw' ----
            {
                f32x4 p0 = {0,0,0,0}, p1 = {0,0,0,0}, p2 = {0,0,0,0}, p3 = {0,0,0,0};
#pragma unroll
                for (int kt = 0; kt < 4; ++kt) {
                    const f16x8* VB = (const f16x8*)Vf + ((w * 4 + kt) * 4) * 64 + l;
                    f16x8 b0 = VB[0], b1 = VB[64], b2 = VB[128], b3 = VB[192];
                    f16x8 ah, al;
#pragma unroll
                    for (int e = 0; e < 8; ++e) {
                        float t = xr[kt * 8 + e];
                        _Float16 h = (_Float16)t;
                        ah[e] = h;
                        al[e] = (_Float16)(t - (float)h);
                    }
                    p0 = mfma16(ah, b0, p0); p1 = mfma16(ah, b1, p1);
                    p2 = mfma16(ah, b2, p2); p3 = mfma16(ah, b3, p3);
                    p0 = mfma16(al, b0, p0); p1 = mfma16(al, b1, p1);
                    p2 = mfma16(al, b2, p2); p3 = mfma16(al, b3, p3);
                }
#pragma unroll
                for (int j = 0; j < 4; ++j) {
                    int base = w * 1088 + (g * 4 + j) * 68 + m16;
                    red_p[base]      = p0[j];
                    red_p[base + 16] = p1[j];
                    red_p[base + 32] = p2[j];
                    red_p[base + 48] = p3[j];
                }
            }
            __syncthreads();   // barrier A

            // ---- reduce 8 partials; qhat = (q/32)^2*(1+0.1*tanh(p/32)); write qhat^T frags; sing ----
            {
                const int m = tid & 15, rp = tid >> 4;   // rp 0..31 -> r0 = 2*rp
                const int r0 = rp * 2;
                float qa0 = 0, qa1 = 0, pa0 = 0, pa1 = 0;
#pragma unroll
                for (int w8 = 0; w8 < 8; ++w8) {
                    float2 a = *(const float2*)&red_q[w8 * 1088 + m * 68 + r0];
                    qa0 += a.x; qa1 += a.y;
                    float2 b = *(const float2*)&red_p[w8 * 1088 + m * 68 + r0];
                    pa0 += b.x; pa1 += b.y;
                }
                float qr, pr, qh0, qh1;
                qr = qa0 * 0.03125f; pr = pa0 * 0.03125f; qh0 = qr*qr*(1.0f + 0.1f*tanhf(pr));
                qr = qa1 * 0.03125f; pr = pa1 * 0.03125f; qh1 = qr*qr*(1.0f + 0.1f*tanhf(pr));
                int kt = r0 >> 5, gp = (r0 >> 3) & 3, e0 = r0 & 7;
                *(h2*)&qh_s[(kt * 64 + gp * 16 + m) * 8 + e0] = (h2){(_Float16)qh0, (_Float16)qh1};
                if (tid < 16) {
                    float xn2 = 0.0f;
#pragma unroll
                    for (int k = 0; k < 8; ++k) xn2 += xn_s[k * 16 + tid];
                    sing_s[tid] = (1.0f + 20.0f * expf(-0.1f * xn2)) * 0.03125f;
                }
            }
            __syncthreads();   // barrier B

            // ---- G^T = Wt' * qhat^T over wave's n-eighth; kick v ----
            {
                const f16x8 qb0 = *(const f16x8*)&qh_s[l * 8];
                const f16x8 qb1 = *(const f16x8*)&qh_s[(64 + l) * 8];
                const float ss = sing_s[m16];
#pragma unroll
                for (int kti = 0; kti < 4; ++kti) {
                    const int Nt0 = w * 8 + kti * 2;
                    const f16x8* WA = (const f16x8*)Wf + Nt0 * 128 + l;
                    f16x8 w00 = WA[0], w01 = WA[64], w10 = WA[128], w11 = WA[192];
                    f32x4 accA = {0,0,0,0}, accB = {0,0,0,0};
                    accA = mfma16(w00, qb0, accA);
                    accA = mfma16(w01, qb1, accA);
                    accB = mfma16(w10, qb0, accB);
                    accB = mfma16(w11, qb1, accB);
                    // permute C-frag (n'=g*4+j at col m16) into state layout (n=g*8+e)
#pragma unroll
                    for (int e = 0; e < 8; ++e) {
                        int src = m16 + ((((g & 1) << 1) + (e >> 2)) << 4);
                        float t0 = __shfl(accA[e & 3], src);
                        float t1 = __shfl(accB[e & 3], src);
                        float gval = (g & 2) ? t1 : t0;
                        float fval = (float)fh[kti * 4 + (e >> 1)][e & 1];
                        vr[kti * 8 + e] = fmaf(ddt, fmaf(-gval, ss, fval), vr[kti * 8 + e]);
                    }
                }
            }
        } // sub

        // ---- final drift x += c1*v (C4 == C1) ----
#pragma unroll
        for (int i = 0; i < 32; ++i) xr[i] = fmaf(c1, vr[i], xr[i]);
    } // steps

    // ---- output [x ; v] ----
    {
        float* ox = out + (row0 + m16) * DD + w * 128 + g * 8;
        float* ov = out + vout_off + (row0 + m16) * DD + w * 128 + g * 8;
#pragma unroll
        for (int kt = 0; kt < 4; ++kt) {
            *(float4*)(ox + kt*32)     = (float4){xr[kt*8+0], xr[kt*8+1], xr[kt*8+2], xr[kt*8+3]};
            *(float4*)(ox + kt*32 + 4) = (float4){xr[kt*8+4], xr[kt*8+5], xr[kt*8+6], xr[kt*8+7]};
            *(float4*)(ov + kt*32)     = (float4){vr[kt*8+0], vr[kt*8+1], vr[kt*8+2], vr[kt*8+3]};
            *(float4*)(ov + kt*32 + 4) = (float4){vr[kt*8+4], vr[kt*8+5], vr[kt*8+6], vr[kt*8+7]};
        }
    }
}

extern "C" void kernel_launch(void* const* d_in, const int* in_sizes, int n_in,
                              void* d_out, int out_size, void* d_ws, size_t ws_size,
                              hipStream_t stream) {
    (void)n_in; (void)out_size; (void)ws_size;
    const float* x  = (const float*)d_in[0];
    const float* v  = (const float*)d_in[1];
    const float* f  = (const float*)d_in[2];
    const float* U  = (const float*)d_in[3];
    const float* Wm = (const float*)d_in[4];
    const float* Vw = (const float*)d_in[5];
    const int* steps = (const int*)d_in[6];

    const int Btot = in_sizes[0] / DD;           // 8192
    const long vout_off = (long)Btot * DD;

    double cb = pow(2.0, 1.0 / 3.0);
    double den = 2.0 - cb;
    double w1 = 1.0 / den, w0 = -cb / den;
    double dt = 0.01 * 1.0;
    float c1 = (float)(w1 / 2.0 * dt);
    float c2 = (float)((w0 + w1) / 2.0 * dt);
    float d1 = (float)(w1 * dt);
    float d2 = (float)(w0 * dt);

    hipLaunchKernelGGL(prep_kernel, dim3((3 * 65536 + 255) / 256), dim3(256), 0, stream,
                       U, Vw, Wm, (_Float16*)d_ws);
    hipLaunchKernelGGL(yoshida4, dim3(Btot / 16), dim3(NTH), 0, stream,
                       x, v, f, steps, (const _Float16*)d_ws, (float*)d_out, vout_off,
                       c1, c2, d1, d2);
}

// Round 5
// 456.023 us; speedup vs baseline: 1.4789x; 1.4789x over previous
//
#include <hip/hip_runtime.h>
#include <math.h>

#define DD 1024
#define RR 64
#define NTH 1024   // 16 waves, 16 rows/block, wave w owns k (and n) in [w*64, w*64+64)

typedef _Float16 f16x8 __attribute__((ext_vector_type(8)));
typedef _Float16 h2    __attribute__((ext_vector_type(2)));
typedef float    f32x4 __attribute__((ext_vector_type(4)));

__device__ __forceinline__ f32x4 mfma16(f16x8 a, f16x8 b, f32x4 c) {
    return __builtin_amdgcn_mfma_f32_16x16x32_f16(a, b, c, 0, 0, 0);
}

// prep: hi-only fp16 fragments, matrices scaled x32. (unchanged)
// U  frags [kt0..31][Nt0..3][l][e]:  U[k][col], k=kt*32+(l>>4)*8+e, col=Nt*16+(l&15)
// Vw frags: same layout, at +65536
// Wt frags [Nt0..63][ktr0..1][l][e]: W[r][n],  n=Nt*16+(l&15), r=ktr*32+(l>>4)*8+e  (+131072)
__global__ void prep_kernel(const float* __restrict__ U, const float* __restrict__ Vw,
                            const float* __restrict__ Wm, _Float16* __restrict__ ws)
{
    int tid = blockIdx.x * blockDim.x + threadIdx.x;
    if (tid >= 3 * 65536) return;
    int m = tid >> 16;
    int r = tid & 65535;
    int l = (r >> 3) & 63;
    int e = r & 7;
    int tile = r >> 9;
    float val;
    if (m < 2) {
        int kt = tile >> 2, Nt = tile & 3;
        int k = kt * 32 + (l >> 4) * 8 + e;
        int col = Nt * 16 + (l & 15);
        val = (m == 0 ? U : Vw)[k * RR + col] * 32.0f;
    } else {
        int Nt = tile >> 1, ktr = tile & 1;
        int n = Nt * 16 + (l & 15);
        int rr = ktr * 32 + (l >> 4) * 8 + e;
        val = Wm[rr * DD + n] * 32.0f;
    }
    ws[m * 65536 + r] = (_Float16)val;
}

__global__ __launch_bounds__(NTH, 4)   // 4 waves/EU -> 128-reg budget; demand ~110
void yoshida5(const float* __restrict__ x_in, const float* __restrict__ v_in,
              const float* __restrict__ force, const int* __restrict__ steps_p,
              const _Float16* __restrict__ ws, float* __restrict__ out, long vout_off,
              float c1, float c2, float d1, float d2)
{
    __shared__ float red_q[16 * 16 * 68];     // [wave][batch-row][r] stride 68  (69.6 KB)
    __shared__ float red_p[16 * 16 * 68];     // 69.6 KB
    __shared__ _Float16 qh_s[2 * 64 * 8];     // qhat^T B-frags (hi fp16)
    __shared__ float xn_s[16 * 16];
    __shared__ float sing_s[16];

    const int tid = threadIdx.x;
    const int w = tid >> 6, l = tid & 63;
    const int m16 = l & 15, g = l >> 4;
    const long row0 = (long)blockIdx.x * 16;

    const _Float16* __restrict__ Uf = ws;
    const _Float16* __restrict__ Vf = ws + 65536;
    const _Float16* __restrict__ Wf = ws + 131072;

    float xr[16], vr[16];     // wave's k-sixteenth of 16 rows, A-frag layout
    h2 fh[8];                 // force slice, fp16 pairs

    {
        const float* xp = x_in + (row0 + m16) * DD + w * 64 + g * 8;
        const float* vp = v_in + (row0 + m16) * DD + w * 64 + g * 8;
        const float* fp = force + (row0 + m16) * DD + w * 64 + g * 8;
#pragma unroll
        for (int kt = 0; kt < 2; ++kt) {
            float4 a = *(const float4*)(xp + kt * 32);
            float4 b = *(const float4*)(xp + kt * 32 + 4);
            xr[kt*8+0]=a.x; xr[kt*8+1]=a.y; xr[kt*8+2]=a.z; xr[kt*8+3]=a.w;
            xr[kt*8+4]=b.x; xr[kt*8+5]=b.y; xr[kt*8+6]=b.z; xr[kt*8+7]=b.w;
            float4 c = *(const float4*)(vp + kt * 32);
            float4 d = *(const float4*)(vp + kt * 32 + 4);
            vr[kt*8+0]=c.x; vr[kt*8+1]=c.y; vr[kt*8+2]=c.z; vr[kt*8+3]=c.w;
            vr[kt*8+4]=d.x; vr[kt*8+5]=d.y; vr[kt*8+6]=d.z; vr[kt*8+7]=d.w;
            float4 e4 = *(const float4*)(fp + kt * 32);
            float4 e5 = *(const float4*)(fp + kt * 32 + 4);
            fh[kt*4+0] = (h2){(_Float16)e4.x, (_Float16)e4.y};
            fh[kt*4+1] = (h2){(_Float16)e4.z, (_Float16)e4.w};
            fh[kt*4+2] = (h2){(_Float16)e5.x, (_Float16)e5.y};
            fh[kt*4+3] = (h2){(_Float16)e5.z, (_Float16)e5.w};
        }
    }
    const int nsteps = steps_p[0];

    for (int s = 0; s < nsteps; ++s) {
#pragma unroll 1
        for (int sub = 0; sub < 3; ++sub) {
            const float cdt = (sub == 0) ? c1 : c2;
            const float ddt = (sub == 1) ? d2 : d1;

            // ---- drift x += cdt*v (registers) + ||x||^2 partials ----
            float part = 0.0f;
#pragma unroll
            for (int i = 0; i < 16; ++i) {
                float xn = fmaf(cdt, vr[i], xr[i]);
                xr[i] = xn;
                part = fmaf(xn, xn, part);
            }
            part += __shfl_xor(part, 16);
            part += __shfl_xor(part, 32);
            if (l < 16) xn_s[w * 16 + l] = part;

            // ---- Q = v @ U' over wave's k-sixteenth (A split hi/lo, B hi) ----
            {
                f32x4 q0 = {0,0,0,0}, q1 = {0,0,0,0}, q2 = {0,0,0,0}, q3 = {0,0,0,0};
#pragma unroll
                for (int kt = 0; kt < 2; ++kt) {
                    const f16x8* UB = (const f16x8*)Uf + ((w * 2 + kt) * 4) * 64 + l;
                    f16x8 b0 = UB[0], b1 = UB[64], b2 = UB[128], b3 = UB[192];
                    f16x8 ah, al;
#pragma unroll
                    for (int e = 0; e < 8; ++e) {
                        float t = vr[kt * 8 + e];
                        _Float16 h = (_Float16)t;
                        ah[e] = h;
                        al[e] = (_Float16)(t - (float)h);
                    }
                    q0 = mfma16(ah, b0, q0); q1 = mfma16(ah, b1, q1);
                    q2 = mfma16(ah, b2, q2); q3 = mfma16(ah, b3, q3);
                    q0 = mfma16(al, b0, q0); q1 = mfma16(al, b1, q1);
                    q2 = mfma16(al, b2, q2); q3 = mfma16(al, b3, q3);
                }
#pragma unroll
                for (int j = 0; j < 4; ++j) {
                    int base = w * 1088 + (g * 4 + j) * 68 + m16;
                    red_q[base]      = q0[j];
                    red_q[base + 16] = q1[j];
                    red_q[base + 32] = q2[j];
                    red_q[base + 48] = q3[j];
                }
            }
            // ---- P = x @ Vw' ----
            {
                f32x4 p0 = {0,0,0,0}, p1 = {0,0,0,0}, p2 = {0,0,0,0}, p3 = {0,0,0,0};
#pragma unroll
                for (int kt = 0; kt < 2; ++kt) {
                    const f16x8* VB = (const f16x8*)Vf + ((w * 2 + kt) * 4) * 64 + l;
                    f16x8 b0 = VB[0], b1 = VB[64], b2 = VB[128], b3 = VB[192];
                    f16x8 ah, al;
#pragma unroll
                    for (int e = 0; e < 8; ++e) {
                        float t = xr[kt * 8 + e];
                        _Float16 h = (_Float16)t;
                        ah[e] = h;
                        al[e] = (_Float16)(t - (float)h);
                    }
                    p0 = mfma16(ah, b0, p0); p1 = mfma16(ah, b1, p1);
                    p2 = mfma16(ah, b2, p2); p3 = mfma16(ah, b3, p3);
                    p0 = mfma16(al, b0, p0); p1 = mfma16(al, b1, p1);
                    p2 = mfma16(al, b2, p2); p3 = mfma16(al, b3, p3);
                }
#pragma unroll
                for (int j = 0; j < 4; ++j) {
                    int base = w * 1088 + (g * 4 + j) * 68 + m16;
                    red_p[base]      = p0[j];
                    red_p[base + 16] = p1[j];
                    red_p[base + 32] = p2[j];
                    red_p[base + 48] = p3[j];
                }
            }
            __syncthreads();   // barrier A

            // ---- reduce 16 partials; qhat = (q/32)^2*(1+0.1*tanh(p/32)); write qhat^T frags; sing ----
            {
                const int m = tid & 15, r = tid >> 4;   // r 0..63, one (m,r) per thread
                float qa = 0.0f, pa = 0.0f;
#pragma unroll
                for (int wv = 0; wv < 16; ++wv) {
                    qa += red_q[wv * 1088 + m * 68 + r];
                    pa += red_p[wv * 1088 + m * 68 + r];
                }
                float qr = qa * 0.03125f, pr = pa * 0.03125f;
                float qh = qr * qr * (1.0f + 0.1f * tanhf(pr));
                int kt = r >> 5, gp = (r >> 3) & 3, e0 = r & 7;
                qh_s[(kt * 64 + gp * 16 + m) * 8 + e0] = (_Float16)qh;
                if (tid < 16) {
                    float xn2 = 0.0f;
#pragma unroll
                    for (int k = 0; k < 16; ++k) xn2 += xn_s[k * 16 + tid];
                    sing_s[tid] = (1.0f + 20.0f * expf(-0.1f * xn2)) * 0.03125f;
                }
            }
            __syncthreads();   // barrier B

            // ---- G^T = Wt' * qhat^T over wave's n-sixteenth; kick v ----
            {
                const f16x8 qb0 = *(const f16x8*)&qh_s[l * 8];
                const f16x8 qb1 = *(const f16x8*)&qh_s[(64 + l) * 8];
                const float ss = sing_s[m16];
#pragma unroll
                for (int kti = 0; kti < 2; ++kti) {
                    const int Nt0 = w * 4 + kti * 2;
                    const f16x8* WA = (const f16x8*)Wf + Nt0 * 128 + l;
                    f16x8 w00 = WA[0], w01 = WA[64], w10 = WA[128], w11 = WA[192];
                    f32x4 accA = {0,0,0,0}, accB = {0,0,0,0};
                    accA = mfma16(w00, qb0, accA);
                    accA = mfma16(w01, qb1, accA);
                    accB = mfma16(w10, qb0, accB);
                    accB = mfma16(w11, qb1, accB);
                    // permute C-frag (n'=g*4+j at col m16) into state layout (n=g*8+e)
#pragma unroll
                    for (int e = 0; e < 8; ++e) {
                        int src = m16 + ((((g & 1) << 1) + (e >> 2)) << 4);
                        float t0 = __shfl(accA[e & 3], src);
                        float t1 = __shfl(accB[e & 3], src);
                        float gval = (g & 2) ? t1 : t0;
                        float fval = (float)fh[kti * 4 + (e >> 1)][e & 1];
                        vr[kti * 8 + e] = fmaf(ddt, fmaf(-gval, ss, fval), vr[kti * 8 + e]);
                    }
                }
            }
        } // sub

        // ---- final drift x += c1*v (C4 == C1) ----
#pragma unroll
        for (int i = 0; i < 16; ++i) xr[i] = fmaf(c1, vr[i], xr[i]);
    } // steps

    // ---- output [x ; v] ----
    {
        float* ox = out + (row0 + m16) * DD + w * 64 + g * 8;
        float* ov = out + vout_off + (row0 + m16) * DD + w * 64 + g * 8;
#pragma unroll
        for (int kt = 0; kt < 2; ++kt) {
            *(float4*)(ox + kt*32)     = (float4){xr[kt*8+0], xr[kt*8+1], xr[kt*8+2], xr[kt*8+3]};
            *(float4*)(ox + kt*32 + 4) = (float4){xr[kt*8+4], xr[kt*8+5], xr[kt*8+6], xr[kt*8+7]};
            *(float4*)(ov + kt*32)     = (float4){vr[kt*8+0], vr[kt*8+1], vr[kt*8+2], vr[kt*8+3]};
            *(float4*)(ov + kt*32 + 4) = (float4){vr[kt*8+4], vr[kt*8+5], vr[kt*8+6], vr[kt*8+7]};
        }
    }
}

extern "C" void kernel_launch(void* const* d_in, const int* in_sizes, int n_in,
                              void* d_out, int out_size, void* d_ws, size_t ws_size,
                              hipStream_t stream) {
    (void)n_in; (void)out_size; (void)ws_size;
    const float* x  = (const float*)d_in[0];
    const float* v  = (const float*)d_in[1];
    const float* f  = (const float*)d_in[2];
    const float* U  = (const float*)d_in[3];
    const float* Wm = (const float*)d_in[4];
    const float* Vw = (const float*)d_in[5];
    const int* steps = (const int*)d_in[6];

    const int Btot = in_sizes[0] / DD;           // 8192
    const long vout_off = (long)Btot * DD;

    double cb = pow(2.0, 1.0 / 3.0);
    double den = 2.0 - cb;
    double w1 = 1.0 / den, w0 = -cb / den;
    double dt = 0.01 * 1.0;
    float c1 = (float)(w1 / 2.0 * dt);
    float c2 = (float)((w0 + w1) / 2.0 * dt);
    float d1 = (float)(w1 * dt);
    float d2 = (float)(w0 * dt);

    hipLaunchKernelGGL(prep_kernel, dim3((3 * 65536 + 255) / 256), dim3(256), 0, stream,
                       U, Vw, Wm, (_Float16*)d_ws);
    hipLaunchKernelGGL(yoshida5, dim3(Btot / 16), dim3(NTH), 0, stream,
                       x, v, f, steps, (const _Float16*)d_ws, (float*)d_out, vout_off,
                       c1, c2, d1, d2);
}